// Round 5
// baseline (5116.880 us; speedup 1.0000x reference)
//
#include <hip/hip_runtime.h>

#define S_LEN 8192
#define HID   2048
#define NH    16
#define HD    128
#define BLKC  256
#define QKV_STRIDE 6144
#define EPSV  1e-5f
#define SCALEF 0.08838834764831845f

typedef unsigned short u16;

__device__ __forceinline__ float b2f(u16 u) {
    unsigned int x = ((unsigned int)u) << 16;
    return __uint_as_float(x);
}
__device__ __forceinline__ u16 f2b(float f) {
    unsigned int u = __float_as_uint(f);
    u += 0x7fff + ((u >> 16) & 1);   // round-to-nearest-even
    return (u16)(u >> 16);
}
__device__ __forceinline__ float get_slope(int h) {
    return exp2f(-0.5f * (float)(h + 1)) * 1.00001f;
}

// ---------------------------------------------------------------------------
// Canonize one fp32 tensor to bf16.
// ---------------------------------------------------------------------------
__global__ __launch_bounds__(256) void canonize_kernel(const float* __restrict__ src,
                                                       u16* __restrict__ dst, int n) {
    const int i0 = (blockIdx.x * 256 + threadIdx.x) * 4;
    if (i0 >= n) return;
    const float4 f = *(const float4*)(src + i0);
    ushort4 o;
    o.x = f2b(f.x); o.y = f2b(f.y); o.z = f2b(f.z); o.w = f2b(f.w);
    *(ushort4*)(dst + i0) = o;
}

// ---------------------------------------------------------------------------
// GEMM: C[M][N] = A[M][K] @ B[N][K]^T (+bias). bf16 in, f32 accum.
// OUT_F32=0 -> bf16 C, OUT_F32=1 -> fp32 C. 64x64 tile, 256 thr, 4x4/thr.
// ---------------------------------------------------------------------------
template<int OUT_F32>
__global__ __launch_bounds__(256) void gemm_abt(const u16* __restrict__ A,
                                                const u16* __restrict__ B,
                                                const u16* __restrict__ bias,
                                                void* __restrict__ Cv,
                                                int K, int lda, int ldb, int ldc) {
    __shared__ float As[16][68];
    __shared__ float Bs[16][68];
    const int t  = threadIdx.x;
    const int tx = t & 15, ty = t >> 4;
    const int row0 = blockIdx.y << 6, col0 = blockIdx.x << 6;
    const int lr = t >> 2, lk = (t & 3) << 2;
    const u16* Ap = A + (size_t)(row0 + lr) * lda + lk;
    const u16* Bp = B + (size_t)(col0 + lr) * ldb + lk;
    float acc[4][4] = {};
    for (int k0 = 0; k0 < K; k0 += 16) {
        ushort4 av = *(const ushort4*)(Ap + k0);
        ushort4 bv = *(const ushort4*)(Bp + k0);
        As[lk + 0][lr] = b2f(av.x); As[lk + 1][lr] = b2f(av.y);
        As[lk + 2][lr] = b2f(av.z); As[lk + 3][lr] = b2f(av.w);
        Bs[lk + 0][lr] = b2f(bv.x); Bs[lk + 1][lr] = b2f(bv.y);
        Bs[lk + 2][lr] = b2f(bv.z); Bs[lk + 3][lr] = b2f(bv.w);
        __syncthreads();
#pragma unroll
        for (int kk = 0; kk < 16; ++kk) {
            float4 A4 = *(const float4*)&As[kk][ty << 2];
            float4 B4 = *(const float4*)&Bs[kk][tx << 2];
            float ar[4] = {A4.x, A4.y, A4.z, A4.w};
            float br[4] = {B4.x, B4.y, B4.z, B4.w};
#pragma unroll
            for (int u = 0; u < 4; ++u)
#pragma unroll
                for (int v = 0; v < 4; ++v) acc[u][v] += ar[u] * br[v];
        }
        __syncthreads();
    }
    float bv4[4] = {0.f, 0.f, 0.f, 0.f};
    if (bias != nullptr) {
#pragma unroll
        for (int v = 0; v < 4; ++v) bv4[v] = b2f(bias[col0 + (tx << 2) + v]);
    }
    if (OUT_F32) {
        float* C = (float*)Cv;
#pragma unroll
        for (int u = 0; u < 4; ++u) {
            float4 o = make_float4(acc[u][0] + bv4[0], acc[u][1] + bv4[1],
                                   acc[u][2] + bv4[2], acc[u][3] + bv4[3]);
            *(float4*)(C + (size_t)(row0 + (ty << 2) + u) * ldc + col0 + (tx << 2)) = o;
        }
    } else {
        u16* C = (u16*)Cv;
#pragma unroll
        for (int u = 0; u < 4; ++u) {
            ushort4 o;
            o.x = f2b(acc[u][0] + bv4[0]); o.y = f2b(acc[u][1] + bv4[1]);
            o.z = f2b(acc[u][2] + bv4[2]); o.w = f2b(acc[u][3] + bv4[3]);
            *(ushort4*)(C + (size_t)(row0 + (ty << 2) + u) * ldc + col0 + (tx << 2)) = o;
        }
    }
}

// ---------------------------------------------------------------------------
// Per (local row, head): RMSNorm(q,k) -> RoPE -> q*=SCALE. In place.
// ---------------------------------------------------------------------------
__global__ __launch_bounds__(128) void normrope_kernel(u16* __restrict__ qkvb,
                                                       const u16* __restrict__ qw,
                                                       const u16* __restrict__ kw,
                                                       const int* __restrict__ pos,
                                                       int row0) {
    const int b = blockIdx.x;
    const int s = b >> 4, h = b & 15;
    const int d = threadIdx.x;
    u16* qp = qkvb + (size_t)s * QKV_STRIDE + h * HD + d;
    u16* kp = qp + HID;
    const float q = b2f(*qp), k = b2f(*kp);
    __shared__ float red[128], sq[128], sk[128];
    red[d] = q * q;
    __syncthreads();
    for (int off = 64; off > 0; off >>= 1) {
        if (d < off) red[d] += red[d + off];
        __syncthreads();
    }
    const float qr = rsqrtf(red[0] * (1.f / 128.f) + EPSV);
    __syncthreads();
    red[d] = k * k;
    __syncthreads();
    for (int off = 64; off > 0; off >>= 1) {
        if (d < off) red[d] += red[d + off];
        __syncthreads();
    }
    const float kr = rsqrtf(red[0] * (1.f / 128.f) + EPSV);
    sq[d] = q * qr * b2f(qw[d]);
    sk[d] = k * kr * b2f(kw[d]);
    __syncthreads();
    const int p = pos[row0 + s];
    const int t2 = d & 63;
    const float invf = powf(600000.f, -(float)t2 * (1.f / 64.f));
    const float fr = (float)p * invf;
    const float cs = cosf(fr), sn = sinf(fr);
    float oq, ok;
    if (d < 64) {
        oq = sq[d] * cs - sq[d + 64] * sn;
        ok = sk[d] * cs - sk[d + 64] * sn;
    } else {
        oq = sq[d] * cs + sq[d - 64] * sn;
        ok = sk[d] * cs + sk[d - 64] * sn;
    }
    *qp = f2b(oq * SCALEF);
    *kp = f2b(ok);
}

// ---------------------------------------------------------------------------
// Per (local chunk, head): contrib[d][e] = sum_j exp(-slope*(255-j)) k[j][d] v[j][e]
// ---------------------------------------------------------------------------
__global__ __launch_bounds__(256) void kv_contrib_kernel(const u16* __restrict__ qkvb,
                                                         float* __restrict__ contrib) {
    const int b = blockIdx.x;
    const int c = b >> 4, h = b & 15;
    const float slope = get_slope(h);
    const u16* kb = qkvb + (size_t)c * BLKC * QKV_STRIDE + HID + h * HD;
    const u16* vb = kb + HID;
    const int t = threadIdx.x;
    const int tx = t & 15, ty = t >> 4;
    const int jj = t >> 5, dd = (t & 31) << 2;
    float acc[8][8] = {};
    __shared__ float kf[8][128], vf[8][128];
    for (int j0 = 0; j0 < BLKC; j0 += 8) {
        const float kd = expf(-slope * (float)(BLKC - 1 - (j0 + jj)));
        ushort4 k4 = *(const ushort4*)(kb + (size_t)(j0 + jj) * QKV_STRIDE + dd);
        ushort4 v4 = *(const ushort4*)(vb + (size_t)(j0 + jj) * QKV_STRIDE + dd);
        kf[jj][dd + 0] = b2f(k4.x) * kd; kf[jj][dd + 1] = b2f(k4.y) * kd;
        kf[jj][dd + 2] = b2f(k4.z) * kd; kf[jj][dd + 3] = b2f(k4.w) * kd;
        vf[jj][dd + 0] = b2f(v4.x); vf[jj][dd + 1] = b2f(v4.y);
        vf[jj][dd + 2] = b2f(v4.z); vf[jj][dd + 3] = b2f(v4.w);
        __syncthreads();
#pragma unroll
        for (int j = 0; j < 8; ++j) {
            float4 k0 = *(const float4*)&kf[j][ty << 3];
            float4 k1 = *(const float4*)&kf[j][(ty << 3) + 4];
            float4 v0 = *(const float4*)&vf[j][tx << 3];
            float4 v1 = *(const float4*)&vf[j][(tx << 3) + 4];
            float kr[8] = {k0.x, k0.y, k0.z, k0.w, k1.x, k1.y, k1.z, k1.w};
            float vr[8] = {v0.x, v0.y, v0.z, v0.w, v1.x, v1.y, v1.z, v1.w};
#pragma unroll
            for (int u = 0; u < 8; ++u)
#pragma unroll
                for (int v = 0; v < 8; ++v) acc[u][v] += kr[u] * vr[v];
        }
        __syncthreads();
    }
    float* cb = contrib + ((size_t)(c * NH + h) * HD + (ty << 3)) * HD + (tx << 3);
#pragma unroll
    for (int u = 0; u < 8; ++u) {
        *(float4*)(cb + (size_t)u * HD)     = make_float4(acc[u][0], acc[u][1], acc[u][2], acc[u][3]);
        *(float4*)(cb + (size_t)u * HD + 4) = make_float4(acc[u][4], acc[u][5], acc[u][6], acc[u][7]);
    }
}

// ---------------------------------------------------------------------------
// Scan with carry across super-chunks.
// ---------------------------------------------------------------------------
__global__ __launch_bounds__(256) void kv_scan_kernel(float* __restrict__ buf,
                                                      float* __restrict__ carry,
                                                      int ncs) {
    const int tid = blockIdx.x * 256 + threadIdx.x;   // < NH*HD*HD = 262144
    const int h = tid >> 14;
    const float bd = expf(-get_slope(h) * (float)BLKC);
    float prev = carry[tid];
    for (int c = 0; c < ncs; ++c) {
        const size_t off = (size_t)c * (NH * HD * HD) + tid;
        const float cur = buf[off];
        buf[off] = prev;
        prev = bd * prev + cur;
    }
    carry[tid] = prev;
}

// ---------------------------------------------------------------------------
// Per (local chunk, head, i-tile of 32): intra (QK^T*decay)@V + inter.
// Output in place into the q-slot (own Q tile staged to LDS first).
// ---------------------------------------------------------------------------
__global__ __launch_bounds__(256) void attn_kernel(u16* __restrict__ qkvb,
                                                   const float* __restrict__ kvstates) {
    const int b  = blockIdx.x;
    const int it = b & 7;
    const int h  = (b >> 3) & 15;
    const int c  = b >> 7;
    const float slope = get_slope(h);
    const int t = threadIdx.x;
    const int tx = t & 15, ty = t >> 4;
    __shared__ float qf[32][132], kf[32][132], vf[32][132], Sc[32][36];
    u16* qb = qkvb + (size_t)(c * BLKC + it * 32) * QKV_STRIDE + h * HD;
#pragma unroll
    for (int u = 0; u < 2; ++u) {
        int fi = t + (u << 8);
        int r = fi >> 4, c8 = (fi & 15) << 3;
        int4 raw = *(const int4*)(qb + (size_t)r * QKV_STRIDE + c8);
        const u16* pr = (const u16*)&raw;
#pragma unroll
        for (int x = 0; x < 8; ++x) qf[r][c8 + x] = b2f(pr[x]);
    }
    float acc[2][8]  = {};
    float acc2[2][8] = {};
    const int i0 = ty << 1, j0 = tx << 1;
    for (int jt = 0; jt <= it; ++jt) {
        const u16* kb = qkvb + (size_t)(c * BLKC + jt * 32) * QKV_STRIDE + HID + h * HD;
        const u16* vb = kb + HID;
        __syncthreads();
#pragma unroll
        for (int u = 0; u < 2; ++u) {
            int fi = t + (u << 8);
            int r = fi >> 4, c8 = (fi & 15) << 3;
            int4 kraw = *(const int4*)(kb + (size_t)r * QKV_STRIDE + c8);
            int4 vraw = *(const int4*)(vb + (size_t)r * QKV_STRIDE + c8);
            const u16* kpr = (const u16*)&kraw;
            const u16* vpr = (const u16*)&vraw;
#pragma unroll
            for (int x = 0; x < 8; ++x) {
                kf[r][c8 + x] = b2f(kpr[x]);
                vf[r][c8 + x] = b2f(vpr[x]);
            }
        }
        __syncthreads();
        float s00 = 0.f, s01 = 0.f, s10 = 0.f, s11 = 0.f;
#pragma unroll 8
        for (int d0 = 0; d0 < HD; d0 += 4) {
            float4 qa = *(const float4*)&qf[i0][d0];
            float4 qc = *(const float4*)&qf[i0 + 1][d0];
            float4 ka = *(const float4*)&kf[j0][d0];
            float4 kc = *(const float4*)&kf[j0 + 1][d0];
            s00 += qa.x * ka.x + qa.y * ka.y + qa.z * ka.z + qa.w * ka.w;
            s01 += qa.x * kc.x + qa.y * kc.y + qa.z * kc.z + qa.w * kc.w;
            s10 += qc.x * ka.x + qc.y * ka.y + qc.z * ka.z + qc.w * ka.w;
            s11 += qc.x * kc.x + qc.y * kc.y + qc.z * kc.z + qc.w * kc.w;
        }
        const int ig = it * 32 + i0, jg = jt * 32 + j0;
        const int d00i = ig - jg     > 0 ? ig - jg     : 0;
        const int d01i = ig - jg - 1 > 0 ? ig - jg - 1 : 0;
        const int d10i = ig - jg + 1 > 0 ? ig - jg + 1 : 0;
        const float e00 = expf(-slope * (float)d00i);
        const float e01 = expf(-slope * (float)d01i);
        const float e10 = expf(-slope * (float)d10i);
        Sc[i0][j0]         = (ig     >= jg    ) ? s00 * e00 : 0.f;
        Sc[i0][j0 + 1]     = (ig     >= jg + 1) ? s01 * e01 : 0.f;
        Sc[i0 + 1][j0]     = (ig + 1 >= jg    ) ? s10 * e10 : 0.f;
        Sc[i0 + 1][j0 + 1] = (ig + 1 >= jg + 1) ? s11 * e00 : 0.f;
        __syncthreads();
#pragma unroll
        for (int j = 0; j < 32; ++j) {
            const float sa = Sc[i0][j], sb = Sc[i0 + 1][j];
            float4 v0 = *(const float4*)&vf[j][tx << 3];
            float4 v1 = *(const float4*)&vf[j][(tx << 3) + 4];
            float vv[8] = {v0.x, v0.y, v0.z, v0.w, v1.x, v1.y, v1.z, v1.w};
#pragma unroll
            for (int e = 0; e < 8; ++e) {
                acc[0][e] += sa * vv[e];
                acc[1][e] += sb * vv[e];
            }
        }
    }
    const float* kvb = kvstates + (size_t)(c * NH + h) * (HD * HD);
    for (int dt = 0; dt < 4; ++dt) {
        __syncthreads();
#pragma unroll
        for (int u = 0; u < 4; ++u) {
            int fi = t + (u << 8);
            int r = fi >> 5, c4 = (fi & 31) << 2;
            *(float4*)&kf[r][c4] = *(const float4*)(kvb + (size_t)(dt * 32 + r) * HD + c4);
        }
        __syncthreads();
#pragma unroll
        for (int dd = 0; dd < 32; ++dd) {
            const float qa = qf[i0][dt * 32 + dd];
            const float qc = qf[i0 + 1][dt * 32 + dd];
            float4 v0 = *(const float4*)&kf[dd][tx << 3];
            float4 v1 = *(const float4*)&kf[dd][(tx << 3) + 4];
            float vv[8] = {v0.x, v0.y, v0.z, v0.w, v1.x, v1.y, v1.z, v1.w};
#pragma unroll
            for (int e = 0; e < 8; ++e) {
                acc2[0][e] += qa * vv[e];
                acc2[1][e] += qc * vv[e];
            }
        }
    }
    const float qd[2] = {expf(-slope * (float)(it * 32 + i0 + 1)),
                         expf(-slope * (float)(it * 32 + i0 + 2))};
    u16* op = qb + (tx << 3);
#pragma unroll
    for (int a = 0; a < 2; ++a) {
        ushort4 o1, o2;
        float ov[8];
#pragma unroll
        for (int e = 0; e < 8; ++e) ov[e] = acc[a][e] + qd[a] * acc2[a][e];
        o1.x = f2b(ov[0]); o1.y = f2b(ov[1]); o1.z = f2b(ov[2]); o1.w = f2b(ov[3]);
        o2.x = f2b(ov[4]); o2.y = f2b(ov[5]); o2.z = f2b(ov[6]); o2.w = f2b(ov[7]);
        *(ushort4*)(op + (size_t)(i0 + a) * QKV_STRIDE)     = o1;
        *(ushort4*)(op + (size_t)(i0 + a) * QKV_STRIDE + 4) = o2;
    }
}

// ---------------------------------------------------------------------------
// Group RMSNorm * g_norm_w * sigmoid(g): q-slot x k-slot -> v-slot.
// ---------------------------------------------------------------------------
__global__ __launch_bounds__(256) void gate_kernel(u16* __restrict__ qkvb,
                                                   const u16* __restrict__ gnw) {
    const int b = blockIdx.x;
    const int s = b >> 3, grp = b & 7;
    const int t = threadIdx.x;
    const int j = (grp << 8) + t;
    const size_t base = (size_t)s * QKV_STRIDE;
    const float x = b2f(qkvb[base + j]);
    __shared__ float red[256];
    red[t] = x * x;
    __syncthreads();
    for (int off = 128; off > 0; off >>= 1) {
        if (t < off) red[t] += red[t + off];
        __syncthreads();
    }
    const float rstd = rsqrtf(red[0] * (1.f / 256.f) + EPSV);
    const float gv = b2f(qkvb[base + HID + j]);
    const float yv = x * rstd * b2f(gnw[j]) * (1.f / (1.f + expf(-gv)));
    qkvb[base + 2 * HID + j] = f2b(yv);
}

// ---------------------------------------------------------------------------
extern "C" void kernel_launch(void* const* d_in, const int* in_sizes, int n_in,
                              void* d_out, int out_size, void* d_ws, size_t ws_size,
                              hipStream_t stream) {
    const int* pos = (const int*)d_in[1];
    float* out = (float*)d_out;   // reference output dtype: float32
    char* ws = (char*)d_ws;

    // ---- canonical bf16 input area -------------------------------------
    u16*  c_hs    = (u16*)(ws + 256);                 // 16777216 el
    u16*  c_qkvw  = c_hs   + 16777216;                // 12582912 el
    u16*  c_qkvb  = c_qkvw + 12582912;                // 6144
    u16*  c_qn    = c_qkvb + 6144;                    // 128
    u16*  c_kn    = c_qn   + 128;                     // 128
    u16*  c_gw    = c_kn   + 128;                     // 4194304
    u16*  c_gnw   = c_gw   + 4194304;                 // 2048
    u16*  c_dw    = c_gnw  + 2048;                    // 4194304
    const size_t canon_end = 256 + (size_t)2 * (16777216 + 12582912 + 6144 + 128 + 128 + 4194304 + 2048 + 4194304);
    const size_t work_off = (canon_end + 255) & ~(size_t)255;

    // ---- pick super-chunk size to fit ws -------------------------------
    const size_t MB = 1048576;
    int SCR;
    if      (ws_size >= work_off + (size_t)2048 * QKV_STRIDE * 2 + 9 * MB) SCR = 2048;
    else if (ws_size >= work_off + (size_t)512  * QKV_STRIDE * 2 + 3 * MB) SCR = 512;
    else                                                                    SCR = 256;
    const int NCS = SCR / BLKC;
    const int NSC = S_LEN / SCR;

    u16*   qkvb   = (u16*)(ws + work_off);
    float* states = (float*)(ws + work_off + (size_t)SCR * QKV_STRIDE * 2);
    float* carry  = states + (size_t)NCS * NH * HD * HD;

    const dim3 B256(256);

    // 0) canonize all fp32 float inputs to bf16
    canonize_kernel<<<dim3(16777216 / 1024), B256, 0, stream>>>((const float*)d_in[0], c_hs,   16777216);
    canonize_kernel<<<dim3(12582912 / 1024), B256, 0, stream>>>((const float*)d_in[2], c_qkvw, 12582912);
    canonize_kernel<<<dim3(6),               B256, 0, stream>>>((const float*)d_in[3], c_qkvb, 6144);
    canonize_kernel<<<dim3(1),               B256, 0, stream>>>((const float*)d_in[4], c_qn,   128);
    canonize_kernel<<<dim3(1),               B256, 0, stream>>>((const float*)d_in[5], c_kn,   128);
    canonize_kernel<<<dim3(4194304 / 1024),  B256, 0, stream>>>((const float*)d_in[6], c_gw,   4194304);
    canonize_kernel<<<dim3(2),               B256, 0, stream>>>((const float*)d_in[7], c_gnw,  2048);
    canonize_kernel<<<dim3(4194304 / 1024),  B256, 0, stream>>>((const float*)d_in[8], c_dw,   4194304);

    hipMemsetAsync(carry, 0, (size_t)NH * HD * HD * sizeof(float), stream);

    for (int sc = 0; sc < NSC; ++sc) {
        const int row0 = sc * SCR;
        const u16* hsb = c_hs + (size_t)row0 * HID;
        gemm_abt<0><<<dim3(QKV_STRIDE / 64, SCR / 64), B256, 0, stream>>>(
            hsb, c_qkvw, c_qkvb, qkvb, HID, HID, HID, QKV_STRIDE);
        normrope_kernel<<<dim3(SCR * NH), dim3(128), 0, stream>>>(
            qkvb, c_qn, c_kn, pos, row0);
        kv_contrib_kernel<<<dim3(NCS * NH), B256, 0, stream>>>(qkvb, states);
        kv_scan_kernel<<<dim3(NH * HD * HD / 256), B256, 0, stream>>>(states, carry, NCS);
        attn_kernel<<<dim3(NCS * NH * 8), B256, 0, stream>>>(qkvb, states);
        gemm_abt<0><<<dim3(HID / 64, SCR / 64), B256, 0, stream>>>(
            hsb, c_gw, nullptr, qkvb + HID, HID, HID, HID, QKV_STRIDE);
        gate_kernel<<<dim3(SCR * 8), B256, 0, stream>>>(qkvb, c_gnw);
        gemm_abt<1><<<dim3(HID / 64, SCR / 64), B256, 0, stream>>>(
            qkvb + 2 * HID, c_dw, nullptr, out + (size_t)row0 * HID,
            HID, QKV_STRIDE, HID, HID);
    }
}